// Round 10
// baseline (70.472 us; speedup 1.0000x reference)
//
#include <hip/hip_runtime.h>

#define N_NODES 98304
#define N_EDGES 1572864
#define HIDDEN  64

#define NB      384      // buckets of 256 nodes; bucket = dst >> 8
#define CAP     4608     // payload slots per bucket (mean 4096, sigma 64)
#define NBLK    384      // edge-chunk blocks; CHUNK*NBLK == N_EDGES
#define CHUNK   4096     // edges per chunk
#define TPB_S   512
#define EPT_S   8        // 512*8 = 4096
#define SEG     4        // sibling blocks per bucket (64-node ranges)

#define FP_SCALE 1048576.0f          // 2^20
#define FP_INV   (1.0f / 1048576.0f)

__device__ __forceinline__ float silu_f(float x) {
    return x / (1.0f + __expf(-x));
}

// ---------------- sorted path ----------------

// payload u64: [63:37]=dr(27b) [36:10]=di(27b) [9:2]=local node(8b) [1]=inter flag
// Block-level counting sort in LDS; slot ranges claimed with ONE device atomic
// per (block,bucket); bucket-ordered coalesced copyout into bucket*CAP regions.
__global__ __launch_bounds__(TPB_S) void scatter_kernel(const int* __restrict__ ei,
    const float* __restrict__ ew,
    const float* __restrict__ xr,
    const float* __restrict__ xi,
    const int* __restrict__ comm,
    unsigned* __restrict__ ctr,
    unsigned long long* __restrict__ payload)
{
    __shared__ unsigned long long sorted[CHUNK];   // 32 KB
    __shared__ unsigned short bucketOf[CHUNK];     // 8 KB
    __shared__ unsigned hist[NB];
    __shared__ unsigned localbase[NB];
    __shared__ unsigned baseS[NB];

    const int tid = threadIdx.x, blk = blockIdx.x;
    for (int i = tid; i < NB; i += TPB_S) hist[i] = 0;
    __syncthreads();

    const int ebase = blk * CHUNK;
    unsigned long long pay[EPT_S];
    unsigned pb[EPT_S], pr[EPT_S];
#pragma unroll
    for (int k = 0; k < EPT_S; ++k) {
        const int e = ebase + k * TPB_S + tid;
        const int s = ei[e];
        const int d = ei[N_EDGES + e];
        const float w = ew[e];
        const float vr = xr[s];
        const float vi = xi[s];
        const int dr = __float2int_rn(w * vr * FP_SCALE);
        const int di = __float2int_rn(w * vi * FP_SCALE);
        const unsigned flag = (comm[s] == comm[d]) ? 0u : 1u;
        const unsigned b = (unsigned)d >> 8;
        pb[k] = b;
        pr[k] = atomicAdd(&hist[b], 1u);
        pay[k] = ((unsigned long long)((unsigned)dr & 0x07FFFFFFu) << 37)
               | ((unsigned long long)((unsigned)di & 0x07FFFFFFu) << 10)
               | ((unsigned)(d & 255) << 2) | ((unsigned long long)flag << 1);
    }
    __syncthreads();

    // wave 0: exclusive scan of block-local hist -> localbase
    if (tid < 64) {
        unsigned v[6];
        unsigned s = 0;
#pragma unroll
        for (int m = 0; m < 6; ++m) { v[m] = hist[tid * 6 + m]; s += v[m]; }
        unsigned p = s;
#pragma unroll
        for (int off = 1; off < 64; off <<= 1) {
            unsigned t = __shfl_up(p, off);
            if (tid >= off) p += t;
        }
        unsigned excl = p - s;
#pragma unroll
        for (int m = 0; m < 6; ++m) { unsigned t = v[m]; localbase[tid * 6 + m] = excl; excl += t; }
    }
    __syncthreads();

    // claim this block's slot range in each bucket region (1 atomic per bucket)
    for (int i = tid; i < NB; i += TPB_S)
        baseS[i] = (unsigned)i * CAP + atomicAdd(&ctr[i], hist[i]);
    // place into bucket-sorted LDS order (independent of baseS -> no extra sync)
#pragma unroll
    for (int k = 0; k < EPT_S; ++k) {
        const unsigned pos = localbase[pb[k]] + pr[k];
        sorted[pos] = pay[k];
        bucketOf[pos] = (unsigned short)pb[k];
    }
    __syncthreads();

    // bucket-ordered copyout: runs of ~10.7 entries per bucket
    for (int i = tid; i < CHUNK; i += TPB_S) {
        const unsigned b = bucketOf[i];
        const unsigned slot = baseS[b] + ((unsigned)i - localbase[b]);
        if (slot < ((unsigned)b + 1u) * CAP)    // overflow guard (never in practice)
            payload[slot] = sorted[i];
    }
}

// 4 sibling blocks per bucket, co-located on one XCD via physical round-robin
// swizzle (blk&7 = XCD). Each scans the FULL bucket payload (3 of 4 reads are
// local-L2 hits), LDS-accumulates only its 64-node range, and epilogues its
// contiguous 32 KB output tile. No partial buffer, no extra kernel.
__global__ __launch_bounds__(256) void accum_epilogue_kernel(
    const unsigned long long* __restrict__ payload,
    const unsigned* __restrict__ ctr,
    const float* __restrict__ Wlr, const float* __restrict__ Wli,
    const float* __restrict__ Wgr, const float* __restrict__ Wgi,
    float4* __restrict__ out)
{
    __shared__ int accR[128];   // [64 local nodes][intra/inter]
    __shared__ int accI[128];
    __shared__ float2 w_s[4][32];
    const int tid = threadIdx.x;
    const int x    = blockIdx.x & 7;     // physical XCD (round-robin dispatch)
    const int slot = blockIdx.x >> 3;    // 0..191 within XCD
    const int bucket = x * (NB / 8) + (slot >> 2);
    const int seg    = slot & 3;         // 64-node range within bucket

    if (tid < 128) { accR[tid] = 0; accI[tid] = 0; }
    else {
        const int t = tid - 128;
        const int which = t >> 5, h2 = t & 31;
        const float* W = (which == 0) ? Wlr : (which == 1) ? Wli
                       : (which == 2) ? Wgr : Wgi;
        w_s[which][h2] = ((const float2*)W)[h2];
    }
    __syncthreads();

    unsigned cnt = ctr[bucket];
    if (cnt > CAP) cnt = CAP;
    const unsigned long long* buck = payload + (size_t)bucket * CAP;
    for (unsigned i = tid; i < cnt; i += 256) {
        const unsigned long long p = buck[i];
        const unsigned ln = (unsigned)(p >> 2) & 255u;
        if ((int)(ln >> 6) == seg) {
            const int dr = (int)((long long)p >> 37);
            const int di = (int)(((long long)(p << 27)) >> 37);
            const unsigned idx = ((ln & 63u) << 1) | ((unsigned)(p >> 1) & 1u);
            atomicAdd(&accR[idx], dr);
            atomicAdd(&accI[idx], di);
        }
    }
    __syncthreads();

#pragma unroll
    for (int j = 0; j < 8; ++j) {
        const int idx = j * 256 + tid;    // 0..2047 = local node(0..63) * 32 + h2
        const int ln  = idx >> 5;
        const int h2  = idx & 31;
        const float sr_l = (float)accR[ln * 2 + 0] * FP_INV;
        const float si_l = (float)accI[ln * 2 + 0] * FP_INV;
        const float sr_g = (float)accR[ln * 2 + 1] * FP_INV;
        const float si_g = (float)accI[ln * 2 + 1] * FP_INV;
        const float2 a = w_s[0][h2], c = w_s[1][h2];
        const float2 g = w_s[2][h2], f = w_s[3][h2];
        float4 o;
        {
            const float arl = a.x * sr_l - c.x * si_l;
            const float ail = c.x * sr_l + a.x * si_l;
            const float arg = g.x * sr_g - f.x * si_g;
            const float aig = f.x * sr_g + g.x * si_g;
            o.x = silu_f(arl) + silu_f(arg);
            o.y = silu_f(ail) + silu_f(aig);
        }
        {
            const float arl = a.y * sr_l - c.y * si_l;
            const float ail = c.y * sr_l + a.y * si_l;
            const float arg = g.y * sr_g - f.y * si_g;
            const float aig = f.y * sr_g + g.y * si_g;
            o.z = silu_f(arl) + silu_f(arg);
            o.w = silu_f(ail) + silu_f(aig);
        }
        out[(size_t)bucket * 8192 + (size_t)seg * 2048 + idx] = o;
    }
}

// ---------------- fallback path (R2, used only if ws too small) ----------------

#define FB_SCALE 2097152.0f
#define FB_INV   (1.0f / 2097152.0f)

__global__ void edge_scatter_fb(const int* __restrict__ ei,
                                const float* __restrict__ ew,
                                const int* __restrict__ comm,
                                const float* __restrict__ xr,
                                const float* __restrict__ xi,
                                unsigned long long* __restrict__ P)
{
    const int e = blockIdx.x * blockDim.x + threadIdx.x;
    if (e >= N_EDGES) return;
    const int s = ei[e];
    const int d = ei[N_EDGES + e];
    const float w = ew[e];
    const int dr = __float2int_rn(w * xr[s] * FB_SCALE);
    const int di = __float2int_rn(w * xi[s] * FB_SCALE);
    const unsigned long long delta =
        (unsigned long long)(((long long)dr << 32) + (long long)di);
    const int base = (comm[s] == comm[d]) ? 0 : N_NODES;
    atomicAdd(&P[base + d], delta);
}

__global__ void epilogue_fb(const unsigned long long* __restrict__ P,
                            const float* __restrict__ Wlr,
                            const float* __restrict__ Wli,
                            const float* __restrict__ Wgr,
                            const float* __restrict__ Wgi,
                            float4* __restrict__ out)
{
    const int total = N_NODES * (HIDDEN / 2);
    const int t = blockIdx.x * blockDim.x + threadIdx.x;
    if (t >= total) return;
    const int n = t >> 5, h2 = t & 31;
    float sr_l, si_l, sr_g, si_g;
    {
        const unsigned long long U = P[n];
        const int bi = (int)(unsigned)(U & 0xffffffffULL);
        const int ar = (int)(unsigned)(U >> 32) + (bi < 0 ? 1 : 0);
        sr_l = (float)ar * FB_INV; si_l = (float)bi * FB_INV;
    }
    {
        const unsigned long long U = P[N_NODES + n];
        const int bi = (int)(unsigned)(U & 0xffffffffULL);
        const int ar = (int)(unsigned)(U >> 32) + (bi < 0 ? 1 : 0);
        sr_g = (float)ar * FB_INV; si_g = (float)bi * FB_INV;
    }
    const float2 wlr = ((const float2*)Wlr)[h2];
    const float2 wli = ((const float2*)Wli)[h2];
    const float2 wgr = ((const float2*)Wgr)[h2];
    const float2 wgi = ((const float2*)Wgi)[h2];
    float4 o;
    {
        const float arl = wlr.x * sr_l - wli.x * si_l;
        const float ail = wli.x * sr_l + wlr.x * si_l;
        const float arg = wgr.x * sr_g - wgi.x * si_g;
        const float aig = wgi.x * sr_g + wgr.x * si_g;
        o.x = silu_f(arl) + silu_f(arg);
        o.y = silu_f(ail) + silu_f(aig);
    }
    {
        const float arl = wlr.y * sr_l - wli.y * si_l;
        const float ail = wli.y * sr_l + wlr.y * si_l;
        const float arg = wgr.y * sr_g - wgi.y * si_g;
        const float aig = wgi.y * sr_g + wgr.y * si_g;
        o.z = silu_f(arl) + silu_f(arg);
        o.w = silu_f(ail) + silu_f(aig);
    }
    out[t] = o;
}

extern "C" void kernel_launch(void* const* d_in, const int* in_sizes, int n_in,
                              void* d_out, int out_size, void* d_ws, size_t ws_size,
                              hipStream_t stream) {
    const float* xr   = (const float*)d_in[0];
    const float* xi   = (const float*)d_in[1];
    const int*   ei   = (const int*)d_in[2];
    const float* ew   = (const float*)d_in[3];
    const int*   comm = (const int*)d_in[4];
    const float* Wlr  = (const float*)d_in[5];
    const float* Wli  = (const float*)d_in[6];
    const float* Wgr  = (const float*)d_in[7];
    const float* Wgi  = (const float*)d_in[8];

    const size_t payload_bytes = (size_t)NB * CAP * sizeof(unsigned long long);  // 14.16 MB
    const size_t ctr_bytes     = 4096;                                           // NB u32, padded
    const size_t need = payload_bytes + ctr_bytes;

    if (ws_size >= need) {
        char* p = (char*)d_ws;
        unsigned long long* payload = (unsigned long long*)p;  p += payload_bytes;
        unsigned* ctr               = (unsigned*)p;

        hipMemsetAsync(ctr, 0, NB * sizeof(unsigned), stream);
        hipLaunchKernelGGL(scatter_kernel, dim3(NBLK), dim3(TPB_S), 0, stream,
                           ei, ew, xr, xi, comm, ctr, payload);
        hipLaunchKernelGGL(accum_epilogue_kernel, dim3(NB * SEG), dim3(256), 0, stream,
                           payload, ctr, Wlr, Wli, Wgr, Wgi, (float4*)d_out);
    } else {
        unsigned long long* P = (unsigned long long*)d_ws;
        hipMemsetAsync(P, 0, (size_t)2 * N_NODES * sizeof(unsigned long long), stream);
        hipLaunchKernelGGL(edge_scatter_fb, dim3((N_EDGES + 255) / 256), dim3(256), 0, stream,
                           ei, ew, comm, xr, xi, P);
        const int total = N_NODES * (HIDDEN / 2);
        hipLaunchKernelGGL(epilogue_fb, dim3((total + 255) / 256), dim3(256), 0, stream,
                           P, Wlr, Wli, Wgr, Wgi, (float4*)d_out);
    }
}

// Round 11
// 58.507 us; speedup vs baseline: 1.2045x; 1.2045x over previous
//
#include <hip/hip_runtime.h>

#define N_NODES 98304
#define N_EDGES 1572864
#define HIDDEN  64

#define NB      384      // buckets of 256 nodes; bucket = dst >> 8
#define NBLK    1536     // edge-chunk blocks; CHUNK*NBLK == N_EDGES
#define CHUNK   1024     // edges per chunk (payload region per block)
#define TPB_S   256
#define EPT_S   4        // 256*4 = 1024
#define SEG     4        // accumulation siblings per bucket (chunk subsets)
#define CPS     (NBLK / SEG)   // chunks per sibling = 384

#define FP_SCALE 1048576.0f          // 2^20
#define FP_INV   (1.0f / 1048576.0f)

__device__ __forceinline__ float silu_f(float x) {
    return x / (1.0f + __expf(-x));
}

// ---------------- sorted path ----------------

// pack node table {xr, xi, comm}: one float4 gather per edge in scatter
__global__ __launch_bounds__(256) void prep_kernel(const float* __restrict__ xr,
                                                   const float* __restrict__ xi,
                                                   const int* __restrict__ comm,
                                                   float4* __restrict__ node)
{
    const int n = blockIdx.x * 256 + threadIdx.x;
    if (n < N_NODES) {
        float4 v;
        v.x = xr[n];
        v.y = xi[n];
        v.z = __int_as_float(comm[n]);
        v.w = 0.0f;
        node[n] = v;
    }
}

// payload u64: [63:37]=dr(27b) [36:10]=di(27b) [9:2]=local node(8b) [1]=inter flag
// Block sorts its 1024-edge chunk by bucket in LDS, writes it LINEARLY to its
// private payload region (fully coalesced, NO device atomics), and emits its
// per-bucket start offsets lbT[blk][b] (u16) for the gather stage.
__global__ __launch_bounds__(TPB_S) void scatter_kernel(const int* __restrict__ ei,
    const float* __restrict__ ew,
    const float4* __restrict__ node,
    const int* __restrict__ comm,
    unsigned short* __restrict__ lbT,
    unsigned long long* __restrict__ payload)
{
    __shared__ unsigned long long sorted[CHUNK];   // 8 KB
    __shared__ unsigned hist[NB];                  // 1.5 KB
    __shared__ unsigned localbase[NB];             // 1.5 KB

    const int tid = threadIdx.x, blk = blockIdx.x;
    for (int i = tid; i < NB; i += TPB_S) hist[i] = 0;
    __syncthreads();

    const int ebase = blk * CHUNK;
    unsigned long long pay[EPT_S];
    unsigned pb[EPT_S], pr[EPT_S];
#pragma unroll
    for (int k = 0; k < EPT_S; ++k) {
        const int e = ebase + k * TPB_S + tid;
        const int s = ei[e];
        const int d = ei[N_EDGES + e];
        const float w = ew[e];
        const float4 ns = node[s];
        const int cd = comm[d];
        const int dr = __float2int_rn(w * ns.x * FP_SCALE);
        const int di = __float2int_rn(w * ns.y * FP_SCALE);
        const unsigned flag = (__float_as_int(ns.z) == cd) ? 0u : 1u;
        const unsigned b = (unsigned)d >> 8;
        pb[k] = b;
        pr[k] = atomicAdd(&hist[b], 1u);
        pay[k] = ((unsigned long long)((unsigned)dr & 0x07FFFFFFu) << 37)
               | ((unsigned long long)((unsigned)di & 0x07FFFFFFu) << 10)
               | ((unsigned)(d & 255) << 2) | ((unsigned long long)flag << 1);
    }
    __syncthreads();

    // wave 0: exclusive scan of block-local hist -> localbase
    if (tid < 64) {
        unsigned v[6];
        unsigned s = 0;
#pragma unroll
        for (int m = 0; m < 6; ++m) { v[m] = hist[tid * 6 + m]; s += v[m]; }
        unsigned p = s;
#pragma unroll
        for (int off = 1; off < 64; off <<= 1) {
            unsigned t = __shfl_up(p, off);
            if (tid >= off) p += t;
        }
        unsigned excl = p - s;
#pragma unroll
        for (int m = 0; m < 6; ++m) { unsigned t = v[m]; localbase[tid * 6 + m] = excl; excl += t; }
    }
    __syncthreads();

    // place into bucket-sorted LDS order; write offset table (coalesced u16)
#pragma unroll
    for (int k = 0; k < EPT_S; ++k)
        sorted[localbase[pb[k]] + pr[k]] = pay[k];
    for (int i = tid; i < NB; i += TPB_S)
        lbT[(size_t)blk * NB + i] = (unsigned short)localbase[i];
    __syncthreads();

    // linear, fully-coalesced copyout into this block's private region
    for (int i = tid; i < CHUNK; i += TPB_S)
        payload[(size_t)blk * CHUNK + i] = sorted[i];
}

// 4 sibling blocks per bucket; sibling `seg` gathers this bucket's runs from
// chunks [seg*CPS, (seg+1)*CPS), accumulates into i32 LDS counters (all 256
// nodes x intra/inter), dumps exact integer partials (coalesced 4 KB).
__global__ __launch_bounds__(256) void accum_partial_kernel(
    const unsigned long long* __restrict__ payload,
    const unsigned short* __restrict__ lbT,
    int* __restrict__ partial)
{
    __shared__ int accR[512];
    __shared__ int accI[512];
    const int tid = threadIdx.x;
    const int bucket = blockIdx.x >> 2;
    const int seg = blockIdx.x & 3;
    accR[tid] = 0; accR[tid + 256] = 0;
    accI[tid] = 0; accI[tid + 256] = 0;
    __syncthreads();

    const int c0 = seg * CPS;
    for (int cc = tid; cc < CPS; cc += 256) {
        const int c = c0 + cc;
        const unsigned base = lbT[(size_t)c * NB + bucket];
        const unsigned next = (bucket < NB - 1)
                            ? (unsigned)lbT[(size_t)c * NB + bucket + 1]
                            : (unsigned)CHUNK;
        const unsigned long long* chunkp = payload + (size_t)c * CHUNK;
        for (unsigned i = base; i < next; ++i) {
            const unsigned long long p = chunkp[i];
            const int dr = (int)((long long)p >> 37);
            const int di = (int)(((long long)(p << 27)) >> 37);
            const unsigned idx = (((unsigned)(p >> 2) & 255u) << 1) | ((unsigned)(p >> 1) & 1u);
            atomicAdd(&accR[idx], dr);
            atomicAdd(&accI[idx], di);
        }
    }
    __syncthreads();

    int* base = partial + ((size_t)blockIdx.x << 10);
    base[tid]       = accR[tid];
    base[tid + 256] = accR[tid + 256];
    base[tid + 512] = accI[tid];
    base[tid + 768] = accI[tid + 256];
}

// one block per 32 nodes (3072 blocks): sum 4 integer partials, decode,
// complex-mul + SiLU epilogue, contiguous 16 KB output tile.
__global__ __launch_bounds__(256) void final_epilogue_kernel(
    const int* __restrict__ partial,
    const float* __restrict__ Wlr, const float* __restrict__ Wli,
    const float* __restrict__ Wgr, const float* __restrict__ Wgi,
    float4* __restrict__ out)
{
    __shared__ float sR[32][2];   // [local node][intra/inter]
    __shared__ float sI[32][2];
    __shared__ float2 w_s[4][32];
    const int tid = threadIdx.x, blk = blockIdx.x;
    const int bucket = blk >> 3;          // 8 blocks per 256-node bucket
    const int obase  = (blk & 7) * 32;    // node offset within bucket

    if (tid < 64) {
        const int ln  = tid >> 1;
        const int sel = tid & 1;
        const int aidx = obase * 2 + tid;  // coalesced
        int sumR = 0, sumI = 0;
#pragma unroll
        for (int seg = 0; seg < SEG; ++seg) {
            const int* reg = partial + ((size_t)(bucket * SEG + seg) << 10);
            sumR += reg[aidx];
            sumI += reg[512 + aidx];
        }
        sR[ln][sel] = (float)sumR * FP_INV;
        sI[ln][sel] = (float)sumI * FP_INV;
    } else if (tid >= 128) {
        const int t = tid - 128;
        const int which = t >> 5, h2 = t & 31;
        const float* W = (which == 0) ? Wlr : (which == 1) ? Wli
                       : (which == 2) ? Wgr : Wgi;
        w_s[which][h2] = ((const float2*)W)[h2];
    }
    __syncthreads();

#pragma unroll
    for (int j = 0; j < 4; ++j) {
        const int idx = j * 256 + tid;    // 0..1023 = local node * 32 + h2
        const int ln  = idx >> 5;
        const int h2  = idx & 31;
        const float sr_l = sR[ln][0], si_l = sI[ln][0];
        const float sr_g = sR[ln][1], si_g = sI[ln][1];
        const float2 a = w_s[0][h2], c = w_s[1][h2];
        const float2 g = w_s[2][h2], f = w_s[3][h2];
        float4 o;
        {
            const float arl = a.x * sr_l - c.x * si_l;
            const float ail = c.x * sr_l + a.x * si_l;
            const float arg = g.x * sr_g - f.x * si_g;
            const float aig = f.x * sr_g + g.x * si_g;
            o.x = silu_f(arl) + silu_f(arg);
            o.y = silu_f(ail) + silu_f(aig);
        }
        {
            const float arl = a.y * sr_l - c.y * si_l;
            const float ail = c.y * sr_l + a.y * si_l;
            const float arg = g.y * sr_g - f.y * si_g;
            const float aig = f.y * sr_g + g.y * si_g;
            o.z = silu_f(arl) + silu_f(arg);
            o.w = silu_f(ail) + silu_f(aig);
        }
        out[(size_t)blk * 1024 + idx] = o;
    }
}

// ---------------- fallback path (R2, used only if ws too small) ----------------

#define FB_SCALE 2097152.0f
#define FB_INV   (1.0f / 2097152.0f)

__global__ void edge_scatter_fb(const int* __restrict__ ei,
                                const float* __restrict__ ew,
                                const int* __restrict__ comm,
                                const float* __restrict__ xr,
                                const float* __restrict__ xi,
                                unsigned long long* __restrict__ P)
{
    const int e = blockIdx.x * blockDim.x + threadIdx.x;
    if (e >= N_EDGES) return;
    const int s = ei[e];
    const int d = ei[N_EDGES + e];
    const float w = ew[e];
    const int dr = __float2int_rn(w * xr[s] * FB_SCALE);
    const int di = __float2int_rn(w * xi[s] * FB_SCALE);
    const unsigned long long delta =
        (unsigned long long)(((long long)dr << 32) + (long long)di);
    const int base = (comm[s] == comm[d]) ? 0 : N_NODES;
    atomicAdd(&P[base + d], delta);
}

__global__ void epilogue_fb(const unsigned long long* __restrict__ P,
                            const float* __restrict__ Wlr,
                            const float* __restrict__ Wli,
                            const float* __restrict__ Wgr,
                            const float* __restrict__ Wgi,
                            float4* __restrict__ out)
{
    const int total = N_NODES * (HIDDEN / 2);
    const int t = blockIdx.x * blockDim.x + threadIdx.x;
    if (t >= total) return;
    const int n = t >> 5, h2 = t & 31;
    float sr_l, si_l, sr_g, si_g;
    {
        const unsigned long long U = P[n];
        const int bi = (int)(unsigned)(U & 0xffffffffULL);
        const int ar = (int)(unsigned)(U >> 32) + (bi < 0 ? 1 : 0);
        sr_l = (float)ar * FB_INV; si_l = (float)bi * FB_INV;
    }
    {
        const unsigned long long U = P[N_NODES + n];
        const int bi = (int)(unsigned)(U & 0xffffffffULL);
        const int ar = (int)(unsigned)(U >> 32) + (bi < 0 ? 1 : 0);
        sr_g = (float)ar * FB_INV; si_g = (float)bi * FB_INV;
    }
    const float2 wlr = ((const float2*)Wlr)[h2];
    const float2 wli = ((const float2*)Wli)[h2];
    const float2 wgr = ((const float2*)Wgr)[h2];
    const float2 wgi = ((const float2*)Wgi)[h2];
    float4 o;
    {
        const float arl = wlr.x * sr_l - wli.x * si_l;
        const float ail = wli.x * sr_l + wlr.x * si_l;
        const float arg = wgr.x * sr_g - wgi.x * si_g;
        const float aig = wgi.x * sr_g + wgr.x * si_g;
        o.x = silu_f(arl) + silu_f(arg);
        o.y = silu_f(ail) + silu_f(aig);
    }
    {
        const float arl = wlr.y * sr_l - wli.y * si_l;
        const float ail = wli.y * sr_l + wlr.y * si_l;
        const float arg = wgr.y * sr_g - wgi.y * si_g;
        const float aig = wgi.y * sr_g + wgr.y * si_g;
        o.z = silu_f(arl) + silu_f(arg);
        o.w = silu_f(ail) + silu_f(aig);
    }
    out[t] = o;
}

extern "C" void kernel_launch(void* const* d_in, const int* in_sizes, int n_in,
                              void* d_out, int out_size, void* d_ws, size_t ws_size,
                              hipStream_t stream) {
    const float* xr   = (const float*)d_in[0];
    const float* xi   = (const float*)d_in[1];
    const int*   ei   = (const int*)d_in[2];
    const float* ew   = (const float*)d_in[3];
    const int*   comm = (const int*)d_in[4];
    const float* Wlr  = (const float*)d_in[5];
    const float* Wli  = (const float*)d_in[6];
    const float* Wgr  = (const float*)d_in[7];
    const float* Wgi  = (const float*)d_in[8];

    const size_t payload_bytes = (size_t)N_EDGES * sizeof(unsigned long long);   // 12.58 MB
    const size_t lbT_bytes     = (size_t)NBLK * NB * sizeof(unsigned short);     // 1.18 MB
    const size_t node_bytes    = (size_t)N_NODES * sizeof(float4);               // 1.57 MB
    const size_t partial_bytes = (size_t)NB * SEG * 1024 * sizeof(int);          // 6.29 MB
    const size_t need = payload_bytes + lbT_bytes + node_bytes + partial_bytes;  // ~21.6 MB

    if (ws_size >= need) {
        char* p = (char*)d_ws;
        unsigned long long* payload = (unsigned long long*)p;  p += payload_bytes;
        unsigned short* lbT         = (unsigned short*)p;      p += lbT_bytes;
        float4* node                = (float4*)p;              p += node_bytes;
        int* partial                = (int*)p;

        hipLaunchKernelGGL(prep_kernel, dim3(N_NODES / 256), dim3(256), 0, stream,
                           xr, xi, comm, node);
        hipLaunchKernelGGL(scatter_kernel, dim3(NBLK), dim3(TPB_S), 0, stream,
                           ei, ew, node, comm, lbT, payload);
        hipLaunchKernelGGL(accum_partial_kernel, dim3(NB * SEG), dim3(256), 0, stream,
                           payload, lbT, partial);
        hipLaunchKernelGGL(final_epilogue_kernel, dim3(N_NODES / 32), dim3(256), 0, stream,
                           partial, Wlr, Wli, Wgr, Wgi, (float4*)d_out);
    } else {
        unsigned long long* P = (unsigned long long*)d_ws;
        hipMemsetAsync(P, 0, (size_t)2 * N_NODES * sizeof(unsigned long long), stream);
        hipLaunchKernelGGL(edge_scatter_fb, dim3((N_EDGES + 255) / 256), dim3(256), 0, stream,
                           ei, ew, comm, xr, xi, P);
        const int total = N_NODES * (HIDDEN / 2);
        hipLaunchKernelGGL(epilogue_fb, dim3((total + 255) / 256), dim3(256), 0, stream,
                           P, Wlr, Wli, Wgr, Wgi, (float4*)d_out);
    }
}